// Round 8
// baseline (1558.154 us; speedup 1.0000x reference)
//
#include <hip/hip_runtime.h>
#include <hip/hip_bf16.h>
#include <cstdio>
#include <cstdint>

#define BS_   128
#define T_    128
#define A_    8
#define D_    128
#define H_    512
#define ROWS_ 1024           // BS*A
#define MTOT_ 131072         // BS*T*A
#define SLAB_ (ROWS_ * H_)   // one timestep slab (X or h), elements

typedef __hip_bfloat16 bf16;
typedef __attribute__((ext_vector_type(4))) float f32x4;
typedef __attribute__((ext_vector_type(8))) short s16x8;
typedef __attribute__((ext_vector_type(4))) short s16x4;

__device__ __forceinline__ void async_ld16(const void* g, const void* lds) {
  __builtin_amdgcn_global_load_lds((const __attribute__((address_space(1))) void*)g,
                                   (__attribute__((address_space(3))) void*)lds,
                                   16, 0, 0);
}
__device__ __forceinline__ s16x8 ldg8(const short* p) { return *(const s16x8*)p; }
__device__ __forceinline__ float sigm(float x) { return 1.f / (1.f + __expf(-x)); }
__device__ __forceinline__ float tanh_f(float x) {
  const float e = __expf(2.f * x);            // inf-safe
  return 1.f - 2.f / (e + 1.f);
}
__device__ __forceinline__ s16x8 cvt8(const float* p) {
  const float4 a = ((const float4*)p)[0];
  const float4 b = ((const float4*)p)[1];
  s16x8 r_;
  r_[0] = __builtin_bit_cast(short, __float2bfloat16(a.x));
  r_[1] = __builtin_bit_cast(short, __float2bfloat16(a.y));
  r_[2] = __builtin_bit_cast(short, __float2bfloat16(a.z));
  r_[3] = __builtin_bit_cast(short, __float2bfloat16(a.w));
  r_[4] = __builtin_bit_cast(short, __float2bfloat16(b.x));
  r_[5] = __builtin_bit_cast(short, __float2bfloat16(b.y));
  r_[6] = __builtin_bit_cast(short, __float2bfloat16(b.z));
  r_[7] = __builtin_bit_cast(short, __float2bfloat16(b.w));
  return r_;
}

// obs [b][t][a][d] fp32 -> obsB [t][b*8+a][d] bf16
__global__ __launch_bounds__(256)
void cvt_obs_kernel(const float* __restrict__ src, bf16* __restrict__ dst) {
  const int o = (blockIdx.x * 256 + threadIdx.x) << 2;
  const int d = o & 127, a = (o >> 7) & 7, t = (o >> 10) & 127, b = o >> 17;
  const float4 v = *(const float4*)(src + o);
  s16x4 pk;
  pk[0] = __builtin_bit_cast(short, __float2bfloat16(v.x));
  pk[1] = __builtin_bit_cast(short, __float2bfloat16(v.y));
  pk[2] = __builtin_bit_cast(short, __float2bfloat16(v.z));
  pk[3] = __builtin_bit_cast(short, __float2bfloat16(v.w));
  *(s16x4*)((short*)dst + ((((size_t)t << 10) + (b << 3) + a) << 7) + d) = pk;
}

__global__ __launch_bounds__(256)
void cvt_kernel(const float* __restrict__ src, bf16* __restrict__ dst) {
  const int i = (blockIdx.x * 256 + threadIdx.x) << 2;
  const float4 v = *(const float4*)(src + i);
  s16x4 o;
  o[0] = __builtin_bit_cast(short, __float2bfloat16(v.x));
  o[1] = __builtin_bit_cast(short, __float2bfloat16(v.y));
  o[2] = __builtin_bit_cast(short, __float2bfloat16(v.z));
  o[3] = __builtin_bit_cast(short, __float2bfloat16(v.w));
  *(s16x4*)((short*)dst + i) = o;
}

// bar (16 KiB at spare+256KiB): 64 flag lines (rt,w8) x 32 jt-dwords = 8 KiB,
// rest padding. Vp for t<2 lives at spare+[0,256K).
__global__ __launch_bounds__(256)
void bar_init_kernel(unsigned* __restrict__ bar) {
  const int i = threadIdx.x;
#pragma unroll
  for (int k = 0; k < 8; ++k) bar[(k << 8) + i] = 0u;
}

// ---------------------------------------------------------------------------
// X = relu(obsB @ W1^T + b1)
// ---------------------------------------------------------------------------
__global__ __launch_bounds__(256)
void xgemm_kernel(const bf16* __restrict__ Ag, const bf16* __restrict__ Wg,
                  const float* __restrict__ bias, bf16* __restrict__ Og) {
  const int bid = blockIdx.x;
  const int m0 = (bid >> 2) << 7;
  const int n0 = (bid & 3) << 7;
  const int tid = threadIdx.x;
  const int w = tid >> 6, lane = tid & 63;
  const int r = lane & 15, q = lane >> 4;
  const int wm = w & 1, wn = w >> 1;

  __shared__ short As[128 * 32];
  __shared__ short Bs[128 * 32];

  f32x4 acc[4][4];
  const f32x4 vz = {0.f, 0.f, 0.f, 0.f};
#pragma unroll
  for (int i = 0; i < 4; ++i)
#pragma unroll
    for (int j = 0; j < 4; ++j) acc[i][j] = vz;

  const int lrow = lane >> 2;
  const int kcol = (lane & 3) << 3;

  for (int kt = 0; kt < 4; ++kt) {          // K = 128
    __syncthreads();
    const int kbase = kt << 5;
#pragma unroll
    for (int jj = 0; jj < 2; ++jj) {
      const int c = (w << 1) + jj;
      const int m = (c << 4) + lrow;
      async_ld16(Ag + (size_t)(m0 + m) * D_ + kbase + kcol, &As[c << 9]);
      async_ld16(Wg + (size_t)(n0 + m) * D_ + kbase + kcol, &Bs[c << 9]);
    }
    __syncthreads();

    s16x8 af[4], bfr[4];
#pragma unroll
    for (int x = 0; x < 4; ++x) {
      af[x]  = *(const s16x8*)&As[((wm << 6) + (x << 4) + r) * 32 + (q << 3)];
      bfr[x] = *(const s16x8*)&Bs[((wn << 6) + (x << 4) + r) * 32 + (q << 3)];
    }
#pragma unroll
    for (int i = 0; i < 4; ++i)
#pragma unroll
      for (int j = 0; j < 4; ++j)
        acc[i][j] = __builtin_amdgcn_mfma_f32_16x16x32_bf16(af[i], bfr[j],
                                                            acc[i][j], 0, 0, 0);
  }

#pragma unroll
  for (int j = 0; j < 4; ++j) {
    const int gn = n0 + (wn << 6) + (j << 4) + r;
    const float bb = bias[gn];
#pragma unroll
    for (int i = 0; i < 4; ++i) {
      const int gmb = m0 + (wm << 6) + (i << 4) + (q << 2);
#pragma unroll
      for (int ii = 0; ii < 4; ++ii) {
        const int gm = gmb + ii;
        Og[(size_t)gm * H_ + gn] =
            __float2bfloat16(fmaxf(acc[i][j][ii] + bb, 0.f));
      }
    }
  }
}

// ---------------------------------------------------------------------------
// Persistent GRU scan, round-16: round-6 protocol (proven) + two neutral
// critical-path changes. XCD-local exchange permanently abandoned (3 fails).
//  1. X(t+1) issued at the TOP of step t, BEFORE the flag wait: the poll's
//     implicit vmcnt(0) absorbs the HBM latency+variance that previously
//     stretched the producer->flag shadow every step (straggler-convoy
//     jitter source #1: FETCH ~= X's 134MB streams cold from HBM).
//  2. Value head fused for ALL t (uniform; t=127 special case removed):
//     per-(rt,w)-wave 16-col partials written to Vp(t). Vp(t) for t>=2
//     aliases Hseq slab t-2 INSIDE the writing wave's own 16-row band --
//     provably dead: passing wait(t) means all same-(rt,w) waves consumed
//     slab t-2 for those rows at step t-1. t<2 -> spare region. A small
//     vred kernel (reads 16.8MB) replaces out_kernel (read 134MB).
//  Protocol unchanged from round-6: 64 flag lines, producer vmcnt(0) ->
//  one agent flag store; consumer 32-lane coalesced agent poll.
// ---------------------------------------------------------------------------
__global__ __launch_bounds__(512, 1)
void scan_kernel(const float* __restrict__ Wih32, const float* __restrict__ Whh32,
                 const float* __restrict__ bih, const float* __restrict__ bhh,
                 const float* __restrict__ Wv, const short* __restrict__ Xs,
                 bf16* __restrict__ Hseq, char* __restrict__ spareVp,
                 unsigned* __restrict__ bar) {
  extern __shared__ short sm[];   // [0,24576): Wih  [24576,49152): Whh (lane-packed)

  const int bid = blockIdx.x;
  const int rt = bid & 7, jt = bid >> 3;
  const int j0 = jt << 4;
  const int tid = threadIdx.x;
  const int w = tid >> 6, lane = tid & 63;     // w in 0..7
  const int r = lane & 15, q = lane >> 4;
  const int rw = (rt << 7) + (w << 4);         // wave's 16 rows
  unsigned* __restrict__ flagw = &bar[((rt << 3) + w) << 5];  // 32 jt-dwords

  // ---- Wih + Whh slices fp32 -> bf16, lane-packed into LDS (once) ----
#pragma unroll
  for (int i = 0; i < 6; ++i) {
    const int c = (i << 3) + w;          // chunk 0..47 = (g, kt)
    const int g = c >> 4, kt = c & 15;
    const size_t woff = (size_t)((g << 9) + j0 + r) * H_ + (kt << 5) + (q << 3);
    *(s16x8*)&sm[(c << 9) + (lane << 3)]          = cvt8(Wih32 + woff);
    *(s16x8*)&sm[24576 + (c << 9) + (lane << 3)]  = cvt8(Whh32 + woff);
  }

  const int j = j0 + r;
  const float bR  = bih[j] + bhh[j];
  const float bZ  = bih[512 + j] + bhh[512 + j];
  const float bIN = bih[1024 + j];
  const float bHN = bhh[1024 + j];
  const float wvj = Wv[j];

  float hm[4] = {0.f, 0.f, 0.f, 0.f};
  const f32x4 vz = {0.f, 0.f, 0.f, 0.f};

  const size_t aoff0 = (size_t)(rw + r) * H_ + (q << 3);
  short* Hs = (short*)Hseq;

  __syncthreads();   // LDS staged (only barrier in the kernel)

  // ---- prologue: gi(0) from X slab 0, pinned full-depth issue ----
  f32x4 gia[3];
  {
    const short* xb = Xs;
    s16x8 ax[16];
#pragma unroll
    for (int p = 0; p < 16; ++p) ax[p] = ldg8(xb + aoff0 + (p << 5));
    __builtin_amdgcn_sched_barrier(0);
#pragma unroll
    for (int g = 0; g < 3; ++g) gia[g] = vz;
#pragma unroll
    for (int kt = 0; kt < 16; ++kt)
#pragma unroll
      for (int g = 0; g < 3; ++g) {
        const s16x8 b = *(const s16x8*)&sm[(((g << 4) + kt) << 9) + (lane << 3)];
        gia[g] = __builtin_amdgcn_mfma_f32_16x16x32_bf16(ax[kt], b, gia[g], 0, 0, 0);
      }
  }

  for (int t = 0; t < T_; ++t) {
    const bool last = (t == T_ - 1);

    // ---- X(t+1) issue FIRST: HBM latency drains inside the wait ----
    s16x8 ax[16];
    if (!last) {
      const short* xb = Xs + (size_t)(t + 1) * SLAB_;
#pragma unroll
      for (int p = 0; p < 16; ++p) ax[p] = ldg8(xb + aoff0 + (p << 5));
      __builtin_amdgcn_sched_barrier(0);   // keep issued; nothing crosses
    }

    // ---- per-wave-slot wait: one coalesced flag-line read per check ----
    f32x4 gha[3];
#pragma unroll
    for (int g = 0; g < 3; ++g) gha[g] = vz;
    if (t > 0) {
      const unsigned tgt = (unsigned)t;
      unsigned spins = 0;
      for (;;) {
        const unsigned fl = __hip_atomic_load(&flagw[lane & 31],
                                              __ATOMIC_RELAXED,
                                              __HIP_MEMORY_SCOPE_AGENT);
        if (__all((int)(fl >= tgt))) break;
        __builtin_amdgcn_s_sleep(1);
        if (++spins > 8000000u) break;                    // dead-man valve
      }

      // ---- gh: all 16 h-loads in flight (pinned) + LDS Whh B-frags ----
      const short* hb = Hs + (size_t)(t - 1) * SLAB_;
      s16x8 ah[16];
#pragma unroll
      for (int p = 0; p < 16; ++p) ah[p] = ldg8(hb + aoff0 + (p << 5));
      __builtin_amdgcn_sched_barrier(0); // keep loads issued & live
#pragma unroll
      for (int kt = 0; kt < 16; ++kt)
#pragma unroll
        for (int g = 0; g < 3; ++g) {
          const s16x8 b = *(const s16x8*)&sm[24576 + (((g << 4) + kt) << 9) + (lane << 3)];
          gha[g] = __builtin_amdgcn_mfma_f32_16x16x32_bf16(ah[kt], b, gha[g], 0, 0, 0);
        }
    }

    // ---- gates, h update, value partials (ALL t) ----
    short* hrow = Hs + (size_t)t * SLAB_;
    // Vp(t) target: t>=2 aliases Hseq slab t-2, this wave's 16-row band
    // (dead by the wait(t) argument); t<2 -> spare.
    float* vpb = (t >= 2)
        ? (float*)((char*)Hs + (size_t)(t - 2) * (SLAB_ * 2) + (size_t)rw * 1024)
        : (float*)(spareVp + (size_t)t * 131072 + (size_t)(rw >> 4) * 2048);
#pragma unroll
    for (int ii = 0; ii < 4; ++ii) {
      const int row = rw + (q << 2) + ii;
      const float rr = sigm(gia[0][ii] + gha[0][ii] + bR);
      const float zz = sigm(gia[1][ii] + gha[1][ii] + bZ);
      const float nn = tanh_f(gia[2][ii] + bIN + rr * (gha[2][ii] + bHN));
      const float hnew = (1.f - zz) * nn + zz * hm[ii];
      hm[ii] = hnew;
      if (!last) {
        // packed lane-pair h store (cols j, j^1)
        const unsigned hv =
            (unsigned)(unsigned short)__builtin_bit_cast(unsigned short,
                                                         __float2bfloat16(hnew));
        const unsigned pv = (unsigned)__shfl_xor((int)hv, 1);
        if (!(r & 1)) {
          const unsigned pk = hv | (pv << 16);
          __hip_atomic_store((unsigned*)(hrow + (size_t)row * H_ + j0 + r), pk,
                             __ATOMIC_RELAXED, __HIP_MEMORY_SCOPE_AGENT);
        }
      }
      // value partial: sum over this block's 16 j-cols (r-lanes)
      float vpv = wvj * hnew;
      vpv += __shfl_xor(vpv, 1);
      vpv += __shfl_xor(vpv, 2);
      vpv += __shfl_xor(vpv, 4);
      vpv += __shfl_xor(vpv, 8);
      if (r == 0) vpb[(jt << 4) + (q << 2) + ii] = vpv;
    }

    if (last) break;

    // ---- arrive: drain own h (+Vp) stores, then ONE flag store ----
    asm volatile("s_waitcnt vmcnt(0)" ::: "memory");
    if (lane == 0)
      __hip_atomic_store(&flagw[jt], (unsigned)(t + 1), __ATOMIC_RELAXED,
                         __HIP_MEMORY_SCOPE_AGENT);

    // ---- gi(t+1) in the arrive-shadow (ax already in registers) ----
#pragma unroll
    for (int g = 0; g < 3; ++g) gia[g] = vz;
#pragma unroll
    for (int kt = 0; kt < 16; ++kt)
#pragma unroll
      for (int g = 0; g < 3; ++g) {
        const s16x8 b = *(const s16x8*)&sm[(((g << 4) + kt) << 9) + (lane << 3)];
        gia[g] = __builtin_amdgcn_mfma_f32_16x16x32_bf16(ax[kt], b, gia[g], 0, 0, 0);
      }
  }
}

// ---------------------------------------------------------------------------
// vred: out[b][t][a] = bv + sum_jt Vp(t)[jt][row]
// idx = (t, row); Vp(t) at Hseq slab t-2 (t>=2) or spare (t<2).
// ---------------------------------------------------------------------------
__global__ __launch_bounds__(512)
void vred_kernel(const char* __restrict__ Hseq, const char* __restrict__ spare,
                 const float* __restrict__ bv, float* __restrict__ out) {
  const int idx = blockIdx.x * 512 + threadIdx.x;   // 0..131071
  const int t = idx >> 10, row = idx & 1023;
  const float* vp = (t >= 2)
      ? (const float*)(Hseq + (size_t)(t - 2) * (SLAB_ * 2)
                       + (size_t)(row & ~15) * 1024 + ((row & 15) << 2))
      : (const float*)(spare + (size_t)t * 131072
                       + (size_t)(row >> 4) * 2048 + ((row & 15) << 2));
  float s = 0.f;
#pragma unroll
  for (int jt = 0; jt < 32; ++jt) s += vp[jt << 4];
  out[((row >> 3) << 10) + (t << 3) + (row & 7)] = s + bv[0];
}

extern "C" void kernel_launch(void* const* d_in, const int* in_sizes, int n_in,
                              void* d_out, int out_size, void* d_ws, size_t ws_size,
                              hipStream_t stream) {
  (void)in_sizes; (void)n_in; (void)out_size;
  const float* obs = (const float*)d_in[0];
  const float* W1  = (const float*)d_in[1];
  const float* b1  = (const float*)d_in[2];
  const float* Wih = (const float*)d_in[3];
  const float* bih = (const float*)d_in[4];
  const float* Whh = (const float*)d_in[5];
  const float* bhh = (const float*)d_in[6];
  const float* Wv  = (const float*)d_in[7];
  const float* bv  = (const float*)d_in[8];
  float* out = (float*)d_out;

  // ws (256 MiB): Hseq 127 slabs | X 128 slabs | spare 1 MiB
  //   obsB aliases Hseq slabs 0..31, W1B slab 32 (dead before h writes)
  //   spare: [0,256K) Vp for t<2 | [256K,+16K) bar flag lines
  char* ws = (char*)d_ws;
  bf16*  Hseq = (bf16*)ws;                                  // 127 MiB
  bf16*  obsB = Hseq;
  bf16*  W1B  = Hseq + (size_t)32 * SLAB_;
  bf16*  X    = (bf16*)(ws + (size_t)127 * SLAB_ * 2);      // 128 MiB
  char*  spare = ws + (size_t)255 * SLAB_ * 2;              // 1 MiB
  unsigned* bar = (unsigned*)(spare + 262144);              // flag lines
  const size_t need = (size_t)256 * SLAB_ * 2;
  if (ws_size < need) {
    fprintf(stderr, "[kernel_launch] WS TOO SMALL: need %zu have %zu\n",
            need, ws_size);
    fflush(stderr);
  }

  hipFuncSetAttribute((const void*)scan_kernel,
                      hipFuncAttributeMaxDynamicSharedMemorySize, 98304);

  cvt_obs_kernel<<<16384, 256, 0, stream>>>(obs, obsB);
  cvt_kernel<<<64, 256, 0, stream>>>(W1, W1B);
  bar_init_kernel<<<1, 256, 0, stream>>>(bar);
  xgemm_kernel<<<4096, 256, 0, stream>>>(obsB, W1B, b1, X);
  // 96 KB dyn-LDS (Wih 48K + Whh 48K) pins 1 block/CU; 8 waves = 2/SIMD
  scan_kernel<<<256, 512, 98304, stream>>>(Wih, Whh, bih, bhh, Wv, (const short*)X,
                                           Hseq, spare, bar);
  vred_kernel<<<256, 512, 0, stream>>>((const char*)Hseq, (const char*)spare,
                                       bv, out);
}